// Round 3
// baseline (552.988 us; speedup 1.0000x reference)
//
#include <hip/hip_runtime.h>
#include <cstdint>
#include <cstddef>

#define NE 600000
#define NN 100000

typedef __attribute__((ext_vector_type(8)))  __bf16         bf16x8;
typedef __attribute__((ext_vector_type(16))) float          f32x16;
typedef __attribute__((ext_vector_type(8)))  unsigned short u16x8;
typedef __attribute__((ext_vector_type(2)))  float          f32x2;

__device__ inline unsigned short f2bf(float f) {
    unsigned int u = __builtin_bit_cast(unsigned int, f);
    u += 0x7fffu + ((u >> 16) & 1u);   // round-to-nearest-even
    return (unsigned short)(u >> 16);
}

// Pack W (272x128 f32, row-major) into B-fragment layout:
// Wp[((k>>3)*128 + col)*8 + (k&7)] = bf16(W[k][col])
__global__ void pack_w(const float* __restrict__ W, unsigned short* __restrict__ Wp) {
    int t = blockIdx.x * 256 + threadIdx.x;       // 272*128 = 34816 threads
    if (t >= 272 * 128) return;
    int k = t >> 7, col = t & 127;
    Wp[((k >> 3) * 128 + col) * 8 + (k & 7)] = f2bf(W[t]);
}

// Convert x (100000x128 f32) to bf16 (fallback path only).
__global__ void cvt_x(const float* __restrict__ x, unsigned short* __restrict__ xb) {
    size_t t = (size_t)(blockIdx.x * 256 + threadIdx.x) * 8;
    float4 a = *(const float4*)(x + t);
    float4 b = *(const float4*)(x + t + 4);
    u16x8 o;
    o[0] = f2bf(a.x); o[1] = f2bf(a.y); o[2] = f2bf(a.z); o[3] = f2bf(a.w);
    o[4] = f2bf(b.x); o[5] = f2bf(b.y); o[6] = f2bf(b.z); o[7] = f2bf(b.w);
    *(u16x8*)(xb + t) = o;
}

// ---------------------------------------------------------------------------
// Decoupled arch v3.
// node_mm: Y = x@W_i, Z = x@W_j once per node (reads f32 x, converts in-reg).
// edge_combine: out[e] = Y[src] + Z[dst] + (ea@W_e + b).
//   v3: ei/ea fetched as wave-uniform SCALAR loads (readfirstlane-forced) ->
//   no readlanes, no VGPR staging of ea; W_e cols + bias held in VGPRs;
//   explicit double-buffered 2x8-edge gather pipeline with only 8-bounded
//   fully-static loops (compiler cannot collapse it).
// ---------------------------------------------------------------------------

__global__ __launch_bounds__(256, 2) void node_mm(
    const float* __restrict__ x,                // NN x 128 f32
    const unsigned short* __restrict__ Wp,      // packed W fragments
    float* __restrict__ Y,                      // NN x 128 f32
    float* __restrict__ Z)                      // NN x 128 f32
{
    const int lane = threadIdx.x & 63;
    const int wave = threadIdx.x >> 6;
    const int r = lane & 31;
    const int h = lane >> 5;
    const int nb = (blockIdx.x * 4 + wave) * 32;
    if (nb >= NN) return;                       // wave-uniform

    const bf16x8* Wg = (const bf16x8*)Wp;
    f32x16 accY[4], accZ[4];
#pragma unroll
    for (int t = 0; t < 4; ++t)
#pragma unroll
        for (int i = 0; i < 16; ++i) { accY[t][i] = 0.f; accZ[t][i] = 0.f; }

    const float4* ax4 = (const float4*)(x + (size_t)(nb + r) * 128);
#pragma unroll
    for (int S = 0; S < 8; ++S) {
        const int kb = 2 * S + h;               // k-chunk of 8 for this half-wave
        float4 pp = ax4[kb * 2], qq = ax4[kb * 2 + 1];
        u16x8 o;
        o[0] = f2bf(pp.x); o[1] = f2bf(pp.y); o[2] = f2bf(pp.z); o[3] = f2bf(pp.w);
        o[4] = f2bf(qq.x); o[5] = f2bf(qq.y); o[6] = f2bf(qq.z); o[7] = f2bf(qq.w);
        bf16x8 a = __builtin_bit_cast(bf16x8, o);
#pragma unroll
        for (int t = 0; t < 4; ++t) {
            accY[t] = __builtin_amdgcn_mfma_f32_32x32x16_bf16(
                          a, Wg[kb * 128 + t * 32 + r],        accY[t], 0, 0, 0);
            accZ[t] = __builtin_amdgcn_mfma_f32_32x32x16_bf16(
                          a, Wg[(16 + kb) * 128 + t * 32 + r], accZ[t], 0, 0, 0);
        }
    }

#pragma unroll
    for (int t = 0; t < 4; ++t)
#pragma unroll
        for (int i = 0; i < 16; ++i) {
            int row = (i & 3) + 8 * (i >> 2) + 4 * h;
            Y[(size_t)(nb + row) * 128 + t * 32 + r] = accY[t][i];
            Z[(size_t)(nb + row) * 128 + t * 32 + r] = accZ[t][i];
        }
}

// Wave owns 64 consecutive edges; lane owns output cols {2*lane, 2*lane+1}.
__global__ __launch_bounds__(256, 4) void edge_combine(
    const float* __restrict__ Y,                // NN x 128 f32
    const float* __restrict__ Z,                // NN x 128 f32
    const int*   __restrict__ ei,               // 2 x NE (int32)
    const float* __restrict__ ea,               // NE x 16
    const float* __restrict__ W,                // 272 x 128 f32 (raw)
    const float* __restrict__ bias,             // 128
    float* __restrict__ out)                    // NE x 128
{
    const int lane = threadIdx.x & 63;
    const int w = (blockIdx.x * 256 + threadIdx.x) >> 6;    // global wave id
    if (w >= NE / 64) return;                   // 9375 waves cover NE exactly
    // Force wave-uniformity so ei/ea accesses become SGPR (s_load) traffic.
    const int eb = __builtin_amdgcn_readfirstlane(w * 64);

    // ---- loop-invariant per-lane state ----
    f32x2 we[16];                               // W_e column pair (32 VGPR)
#pragma unroll
    for (int k = 0; k < 16; ++k)
        we[k] = *(const f32x2*)(W + (size_t)(256 + k) * 128 + 2 * lane);
    const f32x2 bv = *(const f32x2*)(bias + 2 * lane);

    // Gather one edge's Y/Z rows (uniform row base -> saddr-form load).
#define LOAD1(Yd, Zd, i, g) do {                                              \
        int s_ = ei[eb + (g) * 8 + (i)];                                      \
        int d_ = ei[NE + eb + (g) * 8 + (i)];                                 \
        Yd[i] = *(const f32x2*)(Y + ((size_t)s_ << 7) + 2 * lane);            \
        Zd[i] = *(const f32x2*)(Z + ((size_t)d_ << 7) + 2 * lane);            \
    } while (0)

    // Compute+store edge i of group g; optionally refill slot i for group g+2.
#define STEP(Ys, Zs, i, g, refill) do {                                       \
        f32x2 y_ = Ys[i], z_ = Zs[i];                                         \
        if (refill) LOAD1(Ys, Zs, i, (g) + 2);                                \
        const float* ep_ = ea + (size_t)(eb + (g) * 8 + (i)) * 16;            \
        f32x2 acc_ = bv;                                                      \
        _Pragma("unroll")                                                     \
        for (int k_ = 0; k_ < 16; ++k_) acc_ += we[k_] * ep_[k_];             \
        f32x2 o_ = acc_ + y_ + z_;                                            \
        __builtin_nontemporal_store(o_,                                       \
            (f32x2*)(out + ((size_t)(eb + (g) * 8 + (i)) << 7) + 2 * lane));  \
    } while (0)

    f32x2 Ya[8], Za[8], Yb[8], Zb[8];
#pragma unroll
    for (int i = 0; i < 8; ++i) LOAD1(Ya, Za, i, 0);
#pragma unroll
    for (int i = 0; i < 8; ++i) LOAD1(Yb, Zb, i, 1);

#pragma unroll
    for (int g = 0; g < 8; ++g) {
        const bool rf = (g + 2 < 8);
        if ((g & 1) == 0) {
#pragma unroll
            for (int i = 0; i < 8; ++i) STEP(Ya, Za, i, g, rf);
        } else {
#pragma unroll
            for (int i = 0; i < 8; ++i) STEP(Yb, Zb, i, g, rf);
        }
    }
#undef LOAD1
#undef STEP
}

// ---------------------------------------------------------------------------
// Fallback path (previous verified kernels) if workspace is too small.
// ---------------------------------------------------------------------------

#define WAIT_VM(n) do { asm volatile("" ::: "memory");                      \
                        __builtin_amdgcn_s_waitcnt(0x0F70 | (n));           \
                        asm volatile("" ::: "memory"); } while (0)

__global__ __launch_bounds__(256, 2) void edge_mm2(
    const unsigned short* __restrict__ xb,
    const unsigned short* __restrict__ Wp,
    const int* __restrict__ ei,
    const float* __restrict__ ea,
    const float* __restrict__ bias,
    float* __restrict__ out)
{
    __shared__ __attribute__((aligned(16))) unsigned short Abuf[4][2][32][128];

    const int lane = threadIdx.x & 63;
    const int wave = threadIdx.x >> 6;
    const int r  = lane & 31;
    const int h  = lane >> 5;
    const int g4 = lane >> 4;
    const int sl = lane & 15;
    const int ebase = blockIdx.x * 128 + wave * 32;
    if (ebase >= NE) return;
    const int e = ebase + r;

#pragma unroll
    for (int i = 0; i < 8; ++i) {
        int row = 4 * i + g4;
        int nidx = ei[ebase + row];
        const unsigned short* gs = xb + (size_t)nidx * 128 + ((sl ^ (row & 15)) << 3);
        __builtin_amdgcn_global_load_lds(
            (const __attribute__((address_space(1))) void*)gs,
            (__attribute__((address_space(3))) void*)&Abuf[wave][0][4 * i][0],
            16, 0, 0);
    }
#pragma unroll
    for (int i = 0; i < 8; ++i) {
        int row = 4 * i + g4;
        int nidx = ei[NE + ebase + row];
        const unsigned short* gs = xb + (size_t)nidx * 128 + ((sl ^ (row & 15)) << 3);
        __builtin_amdgcn_global_load_lds(
            (const __attribute__((address_space(1))) void*)gs,
            (__attribute__((address_space(3))) void*)&Abuf[wave][1][4 * i][0],
            16, 0, 0);
    }

    const float4* ae = (const float4*)(ea + (size_t)e * 16);
    float4 p = ae[2 * h], q = ae[2 * h + 1];

    f32x16 acc[4];
#pragma unroll
    for (int t = 0; t < 4; ++t)
#pragma unroll
        for (int i = 0; i < 16; ++i) acc[t][i] = 0.f;

    const bf16x8* Wg = (const bf16x8*)Wp;
    const int rm = r & 15;

    WAIT_VM(8);
#pragma unroll
    for (int S = 0; S < 8; ++S) {
        int kb = 2 * S + h;
        bf16x8 a = *(const bf16x8*)&Abuf[wave][0][r][(kb ^ rm) << 3];
#pragma unroll
        for (int t = 0; t < 4; ++t) {
            bf16x8 b = Wg[kb * 128 + t * 32 + r];
            acc[t] = __builtin_amdgcn_mfma_f32_32x32x16_bf16(a, b, acc[t], 0, 0, 0);
        }
    }

    WAIT_VM(0);
#pragma unroll
    for (int S = 0; S < 8; ++S) {
        int kb = 2 * S + h;
        bf16x8 a = *(const bf16x8*)&Abuf[wave][1][r][(kb ^ rm) << 3];
#pragma unroll
        for (int t = 0; t < 4; ++t) {
            bf16x8 b = Wg[(16 + kb) * 128 + t * 32 + r];
            acc[t] = __builtin_amdgcn_mfma_f32_32x32x16_bf16(a, b, acc[t], 0, 0, 0);
        }
    }

    {
        u16x8 o;
        o[0] = f2bf(p.x); o[1] = f2bf(p.y); o[2] = f2bf(p.z); o[3] = f2bf(p.w);
        o[4] = f2bf(q.x); o[5] = f2bf(q.y); o[6] = f2bf(q.z); o[7] = f2bf(q.w);
        bf16x8 a = __builtin_bit_cast(bf16x8, o);
#pragma unroll
        for (int t = 0; t < 4; ++t) {
            bf16x8 b = Wg[(32 + h) * 128 + t * 32 + r];
            acc[t] = __builtin_amdgcn_mfma_f32_32x32x16_bf16(a, b, acc[t], 0, 0, 0);
        }
    }

    float* orow = out + (size_t)ebase * 128;
#pragma unroll
    for (int t = 0; t < 4; ++t) {
        float bv = bias[t * 32 + r];
#pragma unroll
        for (int i = 0; i < 16; ++i) {
            int row = (i & 3) + 8 * (i >> 2) + 4 * h;
            orow[(size_t)row * 128 + t * 32 + r] = acc[t][i] + bv;
        }
    }
}

__global__ __launch_bounds__(256, 2) void edge_mm_fb(
    const float* __restrict__ x,
    const unsigned short* __restrict__ Wp,
    const int* __restrict__ ei,
    const float* __restrict__ ea,
    const float* __restrict__ bias,
    float* __restrict__ out)
{
    __shared__ unsigned short Wl[32 * 128 * 8];
    {
        const uint4* Wg = (const uint4*)Wp;
        uint4* Ws = (uint4*)Wl;
#pragma unroll
        for (int i = 0; i < 16; ++i)
            Ws[threadIdx.x + 256 * i] = Wg[threadIdx.x + 256 * i];
    }
    const int lane = threadIdx.x & 63;
    const int wave = threadIdx.x >> 6;
    const int r = lane & 31;
    const int h = lane >> 5;
    const long ebase = (long)blockIdx.x * 128 + wave * 32;
    __syncthreads();
    if (ebase >= NE) return;
    const int e = (int)ebase + r;
    const int src = ei[e];
    const int dst = ei[NE + e];
    f32x16 acc[4];
#pragma unroll
    for (int t = 0; t < 4; ++t)
#pragma unroll
        for (int i = 0; i < 16; ++i) acc[t][i] = 0.f;
    const bf16x8* Wv = (const bf16x8*)Wl;
#pragma unroll
    for (int ph = 0; ph < 2; ++ph) {
        int node = ph ? dst : src;
#pragma unroll
        for (int s = 0; s < 8; ++s) {
            const float4* ax = (const float4*)(x + (size_t)node * 128);
            float4 pp = ax[(2 * s + h) * 2], qq = ax[(2 * s + h) * 2 + 1];
            u16x8 o;
            o[0] = f2bf(pp.x); o[1] = f2bf(pp.y); o[2] = f2bf(pp.z); o[3] = f2bf(pp.w);
            o[4] = f2bf(qq.x); o[5] = f2bf(qq.y); o[6] = f2bf(qq.z); o[7] = f2bf(qq.w);
            bf16x8 a = __builtin_bit_cast(bf16x8, o);
            int S = ph * 8 + s;
#pragma unroll
            for (int t = 0; t < 4; ++t) {
                bf16x8 b = Wv[(2 * S + h) * 128 + t * 32 + r];
                acc[t] = __builtin_amdgcn_mfma_f32_32x32x16_bf16(a, b, acc[t], 0, 0, 0);
            }
        }
    }
    {
        const float4* ae = (const float4*)(ea + (size_t)e * 16);
        float4 pp = ae[2 * h], qq = ae[2 * h + 1];
        u16x8 o;
        o[0] = f2bf(pp.x); o[1] = f2bf(pp.y); o[2] = f2bf(pp.z); o[3] = f2bf(pp.w);
        o[4] = f2bf(qq.x); o[5] = f2bf(qq.y); o[6] = f2bf(qq.z); o[7] = f2bf(qq.w);
        bf16x8 a = __builtin_bit_cast(bf16x8, o);
        const bf16x8* Wg = (const bf16x8*)Wp;
#pragma unroll
        for (int t = 0; t < 4; ++t) {
            bf16x8 b = Wg[(32 + h) * 128 + t * 32 + r];
            acc[t] = __builtin_amdgcn_mfma_f32_32x32x16_bf16(a, b, acc[t], 0, 0, 0);
        }
    }
    float* orow = out + (size_t)ebase * 128;
#pragma unroll
    for (int t = 0; t < 4; ++t) {
        float bv = bias[t * 32 + r];
#pragma unroll
        for (int i = 0; i < 16; ++i) {
            int row = (i & 3) + 8 * (i >> 2) + 4 * h;
            orow[(size_t)row * 128 + t * 32 + r] = acc[t][i] + bv;
        }
    }
}

extern "C" void kernel_launch(void* const* d_in, const int* in_sizes, int n_in,
                              void* d_out, int out_size, void* d_ws, size_t ws_size,
                              hipStream_t stream) {
    const float* x  = (const float*)d_in[0];
    const int*   ei = (const int*)d_in[1];
    const float* ea = (const float*)d_in[2];
    const float* W  = (const float*)d_in[3];
    const float* b  = (const float*)d_in[4];
    float* out = (float*)d_out;

    unsigned short* Wp = (unsigned short*)d_ws;                        // 69,632 B
    float* Yb = (float*)((char*)d_ws + 69632);                         // 51.2 MB
    float* Zb = (float*)((char*)d_ws + 69632 + 51200000);              // 51.2 MB
    unsigned short* xb = (unsigned short*)((char*)d_ws + 69632);       // (mid path)

    const size_t need_mid  = 69632 + (size_t)NN * 128 * 2;
    const size_t need_full = 69632 + 2ull * NN * 128 * 4;

    hipLaunchKernelGGL(pack_w, dim3(136), dim3(256), 0, stream, W, Wp);

    if (ws_size >= need_full) {
        hipLaunchKernelGGL(node_mm, dim3(782), dim3(256), 0, stream, x, Wp, Yb, Zb);
        hipLaunchKernelGGL(edge_combine, dim3(2344), dim3(256), 0, stream,
                           Yb, Zb, ei, ea, W, b, out);
    } else if (ws_size >= need_mid) {
        hipLaunchKernelGGL(cvt_x, dim3(6250), dim3(256), 0, stream, x, xb);
        hipLaunchKernelGGL(edge_mm2, dim3(4688), dim3(256), 0, stream,
                           xb, Wp, ei, ea, b, out);
    } else {
        hipLaunchKernelGGL(edge_mm_fb, dim3(4688), dim3(256), 0, stream,
                           x, Wp, ei, ea, b, out);
    }
}

// Round 4
// 536.440 us; speedup vs baseline: 1.0308x; 1.0308x over previous
//
#include <hip/hip_runtime.h>
#include <cstdint>
#include <cstddef>

#define NE 600000
#define NN 100000

typedef __attribute__((ext_vector_type(8)))  __bf16         bf16x8;
typedef __attribute__((ext_vector_type(16))) float          f32x16;
typedef __attribute__((ext_vector_type(4)))  float          f32x4;
typedef __attribute__((ext_vector_type(8)))  unsigned short u16x8;

__device__ inline unsigned short f2bf(float f) {
    unsigned int u = __builtin_bit_cast(unsigned int, f);
    u += 0x7fffu + ((u >> 16) & 1u);   // round-to-nearest-even
    return (unsigned short)(u >> 16);
}

// Pack W (272x128 f32, row-major) into B-fragment layout:
// Wp[((k>>3)*128 + col)*8 + (k&7)] = bf16(W[k][col])
__global__ void pack_w(const float* __restrict__ W, unsigned short* __restrict__ Wp) {
    int t = blockIdx.x * 256 + threadIdx.x;       // 272*128 = 34816 threads
    if (t >= 272 * 128) return;
    int k = t >> 7, col = t & 127;
    Wp[((k >> 3) * 128 + col) * 8 + (k & 7)] = f2bf(W[t]);
}

// Convert x (100000x128 f32) to bf16 (fallback path only).
__global__ void cvt_x(const float* __restrict__ x, unsigned short* __restrict__ xb) {
    size_t t = (size_t)(blockIdx.x * 256 + threadIdx.x) * 8;
    float4 a = *(const float4*)(x + t);
    float4 b = *(const float4*)(x + t + 4);
    u16x8 o;
    o[0] = f2bf(a.x); o[1] = f2bf(a.y); o[2] = f2bf(a.z); o[3] = f2bf(a.w);
    o[4] = f2bf(b.x); o[5] = f2bf(b.y); o[6] = f2bf(b.z); o[7] = f2bf(b.w);
    *(u16x8*)(xb + t) = o;
}

#define WAIT_VM(n) do { asm volatile("" ::: "memory");                      \
                        __builtin_amdgcn_s_waitcnt(0x0F70 | (n));           \
                        asm volatile("" ::: "memory"); } while (0)

// ---------------------------------------------------------------------------
// Decoupled arch v4.
// node_mm: Y = x@W_i, Z = x@W_j once per node (MFMA, coalesced).
// edge_combine_lds: out[e] = Y[src] + Z[dst] + (ea@W_e + b) built on the
//   PROVEN edge_mm2 skeleton: per-wave 16-edge tile, 16 global_load_lds row
//   gathers in flight (zero VGPR cost -> the register allocator cannot
//   collapse the pipeline), E computed by one 16x16x32 MFMA per 16-col block
//   while gathers fly, single WAIT_VM(0), LDS combine + NT stores.
//   LDS chunk-XOR swizzle (q = (row>>2)&3, applied on the GLOBAL source
//   address; LDS dest stays linear) makes the combine ds_reads conflict-free.
// ---------------------------------------------------------------------------

__global__ __launch_bounds__(256, 2) void node_mm(
    const float* __restrict__ x,                // NN x 128 f32
    const unsigned short* __restrict__ Wp,      // packed W fragments
    float* __restrict__ Y,                      // NN x 128 f32
    float* __restrict__ Z)                      // NN x 128 f32
{
    const int lane = threadIdx.x & 63;
    const int wave = threadIdx.x >> 6;
    const int r = lane & 31;
    const int h = lane >> 5;
    const int nb = (blockIdx.x * 4 + wave) * 32;
    if (nb >= NN) return;                       // wave-uniform

    const bf16x8* Wg = (const bf16x8*)Wp;
    f32x16 accY[4], accZ[4];
#pragma unroll
    for (int t = 0; t < 4; ++t)
#pragma unroll
        for (int i = 0; i < 16; ++i) { accY[t][i] = 0.f; accZ[t][i] = 0.f; }

    const float4* ax4 = (const float4*)(x + (size_t)(nb + r) * 128);
#pragma unroll
    for (int S = 0; S < 8; ++S) {
        const int kb = 2 * S + h;               // k-chunk of 8 for this half-wave
        float4 pp = ax4[kb * 2], qq = ax4[kb * 2 + 1];
        u16x8 o;
        o[0] = f2bf(pp.x); o[1] = f2bf(pp.y); o[2] = f2bf(pp.z); o[3] = f2bf(pp.w);
        o[4] = f2bf(qq.x); o[5] = f2bf(qq.y); o[6] = f2bf(qq.z); o[7] = f2bf(qq.w);
        bf16x8 a = __builtin_bit_cast(bf16x8, o);
#pragma unroll
        for (int t = 0; t < 4; ++t) {
            accY[t] = __builtin_amdgcn_mfma_f32_32x32x16_bf16(
                          a, Wg[kb * 128 + t * 32 + r],        accY[t], 0, 0, 0);
            accZ[t] = __builtin_amdgcn_mfma_f32_32x32x16_bf16(
                          a, Wg[(16 + kb) * 128 + t * 32 + r], accZ[t], 0, 0, 0);
        }
    }

#pragma unroll
    for (int t = 0; t < 4; ++t)
#pragma unroll
        for (int i = 0; i < 16; ++i) {
            int row = (i & 3) + 8 * (i >> 2) + 4 * h;
            Y[(size_t)(nb + row) * 128 + t * 32 + r] = accY[t][i];
            Z[(size_t)(nb + row) * 128 + t * 32 + r] = accZ[t][i];
        }
}

// Block = 256 thr = 4 waves; wave owns 16 edges. LDS = 4 x (16x128 f32) x 2
// = 64 KB -> 2 blocks/CU, 8 waves/CU, 16 async gathers in flight per wave.
__global__ __launch_bounds__(256, 2) void edge_combine_lds(
    const float* __restrict__ Y,                // NN x 128 f32
    const float* __restrict__ Z,                // NN x 128 f32
    const int*   __restrict__ ei,               // 2 x NE (int32)
    const float* __restrict__ ea,               // NE x 16
    const unsigned short* __restrict__ Wp,      // packed W fragments
    const float* __restrict__ bias,             // 128
    float* __restrict__ out)                    // NE x 128
{
    __shared__ __attribute__((aligned(16))) float Ybuf[4][16][128];
    __shared__ __attribute__((aligned(16))) float Zbuf[4][16][128];

    const int lane = threadIdx.x & 63;
    const int wave = threadIdx.x >> 6;
    const int r16  = lane & 15;
    const int h4   = lane >> 4;                 // 0..3
    const int e0   = (blockIdx.x * 4 + wave) * 16;   // 9375*4*16 = NE exactly

    // ---- oldest loads: ea + bias (hot, retire fast) ----
    // a-frag k-slice for 16x16x32: lane holds k = 8*h4 + 0..7; k>=16 -> zero.
    const float* ear = ea + (size_t)(e0 + r16) * 16 + 8 * (h4 & 1);
    float4 eaA = *(const float4*)ear;
    float4 eaB = *(const float4*)(ear + 4);
    float bvt[8];
#pragma unroll
    for (int t = 0; t < 8; ++t) bvt[t] = bias[t * 16 + r16];

    // ---- per-lane node indices (2 edge rows per gather instruction) ----
    int nidxY[8], nidxZ[8];
#pragma unroll
    for (int i = 0; i < 8; ++i) nidxY[i] = ei[e0 + 2 * i + (lane >> 5)];
#pragma unroll
    for (int i = 0; i < 8; ++i) nidxZ[i] = ei[NE + e0 + 2 * i + (lane >> 5)];

    // ---- issue 16 async row gathers (1 KB / instr, 2 rows each) ----
    // LDS slot (lane&31) of row r receives global 16B-chunk ((lane&31) ^ q(r)),
    // q(r) = (r>>2)&3  => combine-phase ds_reads are bank-conflict-free.
#pragma unroll
    for (int i = 0; i < 8; ++i) {
        int row = 2 * i + (lane >> 5);
        int q = (row >> 2) & 3;
        const float* gs = Y + ((size_t)nidxY[i] << 7) + (((lane & 31) ^ q) << 2);
        __builtin_amdgcn_global_load_lds(
            (const __attribute__((address_space(1))) void*)gs,
            (__attribute__((address_space(3))) void*)&Ybuf[wave][2 * i][0],
            16, 0, 0);
    }
#pragma unroll
    for (int i = 0; i < 8; ++i) {
        int row = 2 * i + (lane >> 5);
        int q = (row >> 2) & 3;
        const float* gs = Z + ((size_t)nidxZ[i] << 7) + (((lane & 31) ^ q) << 2);
        __builtin_amdgcn_global_load_lds(
            (const __attribute__((address_space(1))) void*)gs,
            (__attribute__((address_space(3))) void*)&Zbuf[wave][2 * i][0],
            16, 0, 0);
    }

    // ---- E = ea @ W_e + bias while gathers fly (one MFMA per 16 cols) ----
    bf16x8 a;
    {
        u16x8 o;
        o[0] = f2bf(eaA.x); o[1] = f2bf(eaA.y); o[2] = f2bf(eaA.z); o[3] = f2bf(eaA.w);
        o[4] = f2bf(eaB.x); o[5] = f2bf(eaB.y); o[6] = f2bf(eaB.z); o[7] = f2bf(eaB.w);
        if (h4 >= 2) {                          // k >= 16: zero-pad A
#pragma unroll
            for (int j = 0; j < 8; ++j) o[j] = 0;
        }
        a = __builtin_bit_cast(bf16x8, o);
    }
    const bf16x8* Wg = (const bf16x8*)Wp;
    f32x4 acc[8];
#pragma unroll
    for (int t = 0; t < 8; ++t) {
        acc[t][0] = bvt[t]; acc[t][1] = bvt[t]; acc[t][2] = bvt[t]; acc[t][3] = bvt[t];
        // B-frag: k-block 32 + (h4&1) (W_e rows 256..271); h4>=2 lanes' B is
        // mathematically dead (their A slice is zero) but stays in-range.
        bf16x8 b = Wg[(32 + (h4 & 1)) * 128 + t * 16 + r16];
        acc[t] = __builtin_amdgcn_mfma_f32_16x16x32_bf16(a, b, acc[t], 0, 0, 0);
    }

    // ---- drain gathers, combine, store ----
    WAIT_VM(0);
#pragma unroll
    for (int t = 0; t < 8; ++t) {
        const int ct = t * 16 + r16;            // output column
        const int fo = ((((ct >> 2) ^ h4) << 2) | (ct & 3));  // swizzled LDS idx
#pragma unroll
        for (int g = 0; g < 4; ++g) {
            const int er = h4 * 4 + g;          // C row for acc[t][g]; q(er)=h4
            float yv = Ybuf[wave][er][fo];
            float zv = Zbuf[wave][er][fo];
            __builtin_nontemporal_store(
                acc[t][g] + yv + zv,
                out + (size_t)(e0 + er) * 128 + ct);
        }
    }
}

// ---------------------------------------------------------------------------
// Fallback path (previous verified kernels) if workspace is too small.
// ---------------------------------------------------------------------------

__global__ __launch_bounds__(256, 2) void edge_mm2(
    const unsigned short* __restrict__ xb,
    const unsigned short* __restrict__ Wp,
    const int* __restrict__ ei,
    const float* __restrict__ ea,
    const float* __restrict__ bias,
    float* __restrict__ out)
{
    __shared__ __attribute__((aligned(16))) unsigned short Abuf[4][2][32][128];

    const int lane = threadIdx.x & 63;
    const int wave = threadIdx.x >> 6;
    const int r  = lane & 31;
    const int h  = lane >> 5;
    const int g4 = lane >> 4;
    const int sl = lane & 15;
    const int ebase = blockIdx.x * 128 + wave * 32;
    if (ebase >= NE) return;
    const int e = ebase + r;

#pragma unroll
    for (int i = 0; i < 8; ++i) {
        int row = 4 * i + g4;
        int nidx = ei[ebase + row];
        const unsigned short* gs = xb + (size_t)nidx * 128 + ((sl ^ (row & 15)) << 3);
        __builtin_amdgcn_global_load_lds(
            (const __attribute__((address_space(1))) void*)gs,
            (__attribute__((address_space(3))) void*)&Abuf[wave][0][4 * i][0],
            16, 0, 0);
    }
#pragma unroll
    for (int i = 0; i < 8; ++i) {
        int row = 4 * i + g4;
        int nidx = ei[NE + ebase + row];
        const unsigned short* gs = xb + (size_t)nidx * 128 + ((sl ^ (row & 15)) << 3);
        __builtin_amdgcn_global_load_lds(
            (const __attribute__((address_space(1))) void*)gs,
            (__attribute__((address_space(3))) void*)&Abuf[wave][1][4 * i][0],
            16, 0, 0);
    }

    const float4* ae = (const float4*)(ea + (size_t)e * 16);
    float4 p = ae[2 * h], q = ae[2 * h + 1];

    f32x16 acc[4];
#pragma unroll
    for (int t = 0; t < 4; ++t)
#pragma unroll
        for (int i = 0; i < 16; ++i) acc[t][i] = 0.f;

    const bf16x8* Wg = (const bf16x8*)Wp;
    const int rm = r & 15;

    WAIT_VM(8);
#pragma unroll
    for (int S = 0; S < 8; ++S) {
        int kb = 2 * S + h;
        bf16x8 a = *(const bf16x8*)&Abuf[wave][0][r][(kb ^ rm) << 3];
#pragma unroll
        for (int t = 0; t < 4; ++t) {
            bf16x8 b = Wg[kb * 128 + t * 32 + r];
            acc[t] = __builtin_amdgcn_mfma_f32_32x32x16_bf16(a, b, acc[t], 0, 0, 0);
        }
    }

    WAIT_VM(0);
#pragma unroll
    for (int S = 0; S < 8; ++S) {
        int kb = 2 * S + h;
        bf16x8 a = *(const bf16x8*)&Abuf[wave][1][r][(kb ^ rm) << 3];
#pragma unroll
        for (int t = 0; t < 4; ++t) {
            bf16x8 b = Wg[(16 + kb) * 128 + t * 32 + r];
            acc[t] = __builtin_amdgcn_mfma_f32_32x32x16_bf16(a, b, acc[t], 0, 0, 0);
        }
    }

    {
        u16x8 o;
        o[0] = f2bf(p.x); o[1] = f2bf(p.y); o[2] = f2bf(p.z); o[3] = f2bf(p.w);
        o[4] = f2bf(q.x); o[5] = f2bf(q.y); o[6] = f2bf(q.z); o[7] = f2bf(q.w);
        bf16x8 a = __builtin_bit_cast(bf16x8, o);
#pragma unroll
        for (int t = 0; t < 4; ++t) {
            bf16x8 b = Wg[(32 + h) * 128 + t * 32 + r];
            acc[t] = __builtin_amdgcn_mfma_f32_32x32x16_bf16(a, b, acc[t], 0, 0, 0);
        }
    }

    float* orow = out + (size_t)ebase * 128;
#pragma unroll
    for (int t = 0; t < 4; ++t) {
        float bv = bias[t * 32 + r];
#pragma unroll
        for (int i = 0; i < 16; ++i) {
            int row = (i & 3) + 8 * (i >> 2) + 4 * h;
            orow[(size_t)row * 128 + t * 32 + r] = acc[t][i] + bv;
        }
    }
}

__global__ __launch_bounds__(256, 2) void edge_mm_fb(
    const float* __restrict__ x,
    const unsigned short* __restrict__ Wp,
    const int* __restrict__ ei,
    const float* __restrict__ ea,
    const float* __restrict__ bias,
    float* __restrict__ out)
{
    __shared__ unsigned short Wl[32 * 128 * 8];
    {
        const uint4* Wg = (const uint4*)Wp;
        uint4* Ws = (uint4*)Wl;
#pragma unroll
        for (int i = 0; i < 16; ++i)
            Ws[threadIdx.x + 256 * i] = Wg[threadIdx.x + 256 * i];
    }
    const int lane = threadIdx.x & 63;
    const int wave = threadIdx.x >> 6;
    const int r = lane & 31;
    const int h = lane >> 5;
    const long ebase = (long)blockIdx.x * 128 + wave * 32;
    __syncthreads();
    if (ebase >= NE) return;
    const int e = (int)ebase + r;
    const int src = ei[e];
    const int dst = ei[NE + e];
    f32x16 acc[4];
#pragma unroll
    for (int t = 0; t < 4; ++t)
#pragma unroll
        for (int i = 0; i < 16; ++i) acc[t][i] = 0.f;
    const bf16x8* Wv = (const bf16x8*)Wl;
#pragma unroll
    for (int ph = 0; ph < 2; ++ph) {
        int node = ph ? dst : src;
#pragma unroll
        for (int s = 0; s < 8; ++s) {
            const float4* ax = (const float4*)(x + (size_t)node * 128);
            float4 pp = ax[(2 * s + h) * 2], qq = ax[(2 * s + h) * 2 + 1];
            u16x8 o;
            o[0] = f2bf(pp.x); o[1] = f2bf(pp.y); o[2] = f2bf(pp.z); o[3] = f2bf(pp.w);
            o[4] = f2bf(qq.x); o[5] = f2bf(qq.y); o[6] = f2bf(qq.z); o[7] = f2bf(qq.w);
            bf16x8 a = __builtin_bit_cast(bf16x8, o);
            int S = ph * 8 + s;
#pragma unroll
            for (int t = 0; t < 4; ++t) {
                bf16x8 b = Wv[(2 * S + h) * 128 + t * 32 + r];
                acc[t] = __builtin_amdgcn_mfma_f32_32x32x16_bf16(a, b, acc[t], 0, 0, 0);
            }
        }
    }
    {
        const float4* ae = (const float4*)(ea + (size_t)e * 16);
        float4 pp = ae[2 * h], qq = ae[2 * h + 1];
        u16x8 o;
        o[0] = f2bf(pp.x); o[1] = f2bf(pp.y); o[2] = f2bf(pp.z); o[3] = f2bf(pp.w);
        o[4] = f2bf(qq.x); o[5] = f2bf(qq.y); o[6] = f2bf(qq.z); o[7] = f2bf(qq.w);
        bf16x8 a = __builtin_bit_cast(bf16x8, o);
        const bf16x8* Wg = (const bf16x8*)Wp;
#pragma unroll
        for (int t = 0; t < 4; ++t) {
            bf16x8 b = Wg[(32 + h) * 128 + t * 32 + r];
            acc[t] = __builtin_amdgcn_mfma_f32_32x32x16_bf16(a, b, acc[t], 0, 0, 0);
        }
    }
    float* orow = out + (size_t)ebase * 128;
#pragma unroll
    for (int t = 0; t < 4; ++t) {
        float bv = bias[t * 32 + r];
#pragma unroll
        for (int i = 0; i < 16; ++i) {
            int row = (i & 3) + 8 * (i >> 2) + 4 * h;
            orow[(size_t)row * 128 + t * 32 + r] = acc[t][i] + bv;
        }
    }
}

extern "C" void kernel_launch(void* const* d_in, const int* in_sizes, int n_in,
                              void* d_out, int out_size, void* d_ws, size_t ws_size,
                              hipStream_t stream) {
    const float* x  = (const float*)d_in[0];
    const int*   ei = (const int*)d_in[1];
    const float* ea = (const float*)d_in[2];
    const float* W  = (const float*)d_in[3];
    const float* b  = (const float*)d_in[4];
    float* out = (float*)d_out;

    unsigned short* Wp = (unsigned short*)d_ws;                        // 69,632 B
    float* Yb = (float*)((char*)d_ws + 69632);                         // 51.2 MB
    float* Zb = (float*)((char*)d_ws + 69632 + 51200000);              // 51.2 MB
    unsigned short* xb = (unsigned short*)((char*)d_ws + 69632);       // (mid path)

    const size_t need_mid  = 69632 + (size_t)NN * 128 * 2;
    const size_t need_full = 69632 + 2ull * NN * 128 * 4;

    hipLaunchKernelGGL(pack_w, dim3(136), dim3(256), 0, stream, W, Wp);

    if (ws_size >= need_full) {
        hipLaunchKernelGGL(node_mm, dim3(782), dim3(256), 0, stream, x, Wp, Yb, Zb);
        hipLaunchKernelGGL(edge_combine_lds, dim3(9375), dim3(256), 0, stream,
                           Yb, Zb, ei, ea, Wp, b, out);
    } else if (ws_size >= need_mid) {
        hipLaunchKernelGGL(cvt_x, dim3(6250), dim3(256), 0, stream, x, xb);
        hipLaunchKernelGGL(edge_mm2, dim3(4688), dim3(256), 0, stream,
                           xb, Wp, ei, ea, b, out);
    } else {
        hipLaunchKernelGGL(edge_mm_fb, dim3(4688), dim3(256), 0, stream,
                           x, Wp, ei, ea, b, out);
    }
}